// Round 13
// baseline (100.569 us; speedup 1.0000x reference)
//
#include <hip/hip_runtime.h>
#include <math.h>

#define B_ 8
#define C_ 64
#define M_ 512            // B_*C_
#define T_ 1200
#define TP2 1280          // T padded to 128
#define KP 4864           // K padded (K = 4800)
#define K2P 9728          // 2*KP interleaved cos/sin
#define SPLITK 8
#define KCH 1216          // K2P/SPLITK halves
#define NST1 20           // TP2/64 reduction steps (gemm1)
#define NST2 19           // KCH/64 reduction steps (gemm2)
#define TCH 152           // tau t-chunk length (8*152 = 1216)

#ifndef M_PI
#define M_PI 3.14159265358979323846
#endif

typedef _Float16 h8 __attribute__((ext_vector_type(8)));
typedef float f32x16 __attribute__((ext_vector_type(16)));
union H8 { h8 h; float4 v; _Float16 e[8]; };
union HP { _Float16 hh[2]; unsigned u; };
union F4U { float4 v; float f[4]; };

#define Z16v {0.f,0.f,0.f,0.f,0.f,0.f,0.f,0.f,0.f,0.f,0.f,0.f,0.f,0.f,0.f,0.f}
#define MFMA32(a, b, c) __builtin_amdgcn_mfma_f32_32x32x16_f16(a, b, c, 0, 0, 0)

__device__ __forceinline__ float2 cmul(float2 a, float2 b) {
    return make_float2(a.x * b.x - a.y * b.y, a.y * b.x + a.x * b.y);
}

// async global->LDS, 16B per lane (dest resolves to wave base + lane*16)
__device__ __forceinline__ void gload16(const void* g, void* l) {
    __builtin_amdgcn_global_load_lds(
        (const __attribute__((address_space(1))) unsigned int*)g,
        (__attribute__((address_space(3))) unsigned int*)l, 16, 0, 0);
}

__device__ int detect_mode(const void* mask_raw) {
    __shared__ int sb0, sb1;
    if (threadIdx.x == 0) { sb0 = 0; sb1 = 0; }
    __syncthreads();
    const unsigned* wi = (const unsigned*)mask_raw;
    const float* wf = (const float*)mask_raw;
    int nw = (B_ * T_) >> 2;
    int badI = 0, badF = 0;
    for (int i = threadIdx.x; i < nw; i += blockDim.x) {
        unsigned v = wi[i];
        badI |= (v > 1u);
        float f = wf[i];
        badF |= !(f == 0.0f || f == 1.0f);
    }
    if (badI) sb0 = 1;
    if (badF) sb1 = 1;
    __syncthreads();
    return (!sb0) ? 0 : ((!sb1) ? 1 : 2);
}

__device__ __forceinline__ float mval(const void* mask_raw, int mode, int idx) {
    if (mode == 0) return (float)((const int*)mask_raw)[idx];
    if (mode == 1) return ((const float*)mask_raw)[idx];
    return (float)((const unsigned char*)mask_raw)[idx];
}

// ---------------- K1 seed: rot tables (0..113) | mf (114..123) | cnt (124) ----------------
__global__ __launch_bounds__(256) void seed_kernel(
    const void* __restrict__ mask, float* __restrict__ mf, float* __restrict__ cnt,
    float2* __restrict__ rot1, float2* __restrict__ rot8,
    float2* __restrict__ rot32, float2* __restrict__ rot64,
    float2* __restrict__ rot2, float2* __restrict__ rot304, double fstep) {
    int bx = blockIdx.x, tid = threadIdx.x;
    if (bx < 114) {
        int tb = bx / 19;
        int k = (bx % 19) * 256 + tid;     // < 4864
        double om = 2.0 * M_PI * (fstep + (double)k * fstep);
        double w = (double)((float)om);    // reference rounds omega to f32
        double mult = (tb == 0) ? 1.0 : (tb == 1) ? 8.0 : (tb == 2) ? 32.0
                    : (tb == 3) ? 64.0 : (tb == 4) ? 2.0 : 304.0;
        double s, c;
        sincos(mult * w, &s, &c);
        float2 v = make_float2((float)c, (float)s);
        if (tb == 0)      rot1[k] = v;
        else if (tb == 1) rot8[k] = v;
        else if (tb == 2) rot32[k] = v;
        else if (tb == 3) rot64[k] = v;
        else if (tb == 4) rot2[k] = v;
        else              rot304[k] = v;
        return;
    }
    int mode = detect_mode(mask);
    if (bx < 124) {
        // mf convert, vectorized
        int i = ((bx - 114) * 256 + tid) * 4;   // 10 blocks cover 9600
        if (i >= B_ * T_) return;
        F4U o;
        if (mode == 0) {
            int4 v = *(const int4*)((const int*)mask + i);
            o.f[0] = (float)v.x; o.f[1] = (float)v.y; o.f[2] = (float)v.z; o.f[3] = (float)v.w;
        } else if (mode == 1) {
            o.v = *(const float4*)((const float*)mask + i);
        } else {
            unsigned v = *(const unsigned*)((const unsigned char*)mask + i);
            o.f[0] = (float)(v & 0xff); o.f[1] = (float)((v >> 8) & 0xff);
            o.f[2] = (float)((v >> 16) & 0xff); o.f[3] = (float)((v >> 24) & 0xff);
        }
        *(float4*)&mf[i] = o.v;
        return;
    }
    // bx == 124: cnt via per-b block reduction over raw mask (no atomics)
    {
        __shared__ float red[256];
        for (int b = 0; b < B_; b++) {
            float s = 0.f;
            for (int t = tid; t < T_; t += 256) s += mval(mask, mode, b * T_ + t);
            red[tid] = s; __syncthreads();
            for (int w = 128; w > 0; w >>= 1) {
                if (tid < w) red[tid] += red[tid + w];
                __syncthreads();
            }
            if (tid == 0) cnt[b] = red[0];
            __syncthreads();
        }
    }
}

// ---------------- K2 prep2: dm (0..319) | tau (320..471) | basisD (472..1991) ----------------
__global__ __launch_bounds__(256) void prep2_kernel(
    const float* __restrict__ data, const float* __restrict__ mf,
    const float2* __restrict__ rot1t, const float2* __restrict__ rot8t,
    const float2* __restrict__ rot32t, const float2* __restrict__ rot64t,
    const float2* __restrict__ rot2t, const float2* __restrict__ rot304t,
    _Float16* __restrict__ dm, float* __restrict__ partS, float* __restrict__ partC,
    _Float16* __restrict__ Zb, _Float16* __restrict__ ZT, int K) {
    __shared__ float mfS[B_][TCH];            // tau role
    __shared__ _Float16 sZ[128 * 80];         // basisD role
    __shared__ _Float16 sZT[64 * 136];        // basisD role
    int bx = blockIdx.x, tid = threadIdx.x;
    if (bx < 320) {
        // dm: dm[bc][TP2] = f16(data*mf), 8 halves/thread
        int base = (bx * 256 + tid) * 8;
        int t = base % TP2, bc = base / TP2;
        H8 o;
        if (t < T_) {
            int b = bc >> 6;
            F4U d0, d1, m0, m1;
            d0.v = *(const float4*)&data[bc * T_ + t];
            d1.v = *(const float4*)&data[bc * T_ + t + 4];
            m0.v = *(const float4*)&mf[b * T_ + t];
            m1.v = *(const float4*)&mf[b * T_ + t + 4];
#pragma unroll
            for (int e = 0; e < 4; e++) {
                o.e[e]     = (_Float16)(d0.f[e] * m0.f[e]);
                o.e[e + 4] = (_Float16)(d1.f[e] * m1.f[e]);
            }
        } else {
#pragma unroll
            for (int e = 0; e < 8; e++) o.e[e] = (_Float16)0.f;
        }
        *(float4*)&dm[base] = o.v;
        return;
    }
    if (bx < 472) {
        // tau partials
        int i0 = bx - 320;                    // 0..151
        int kb = i0 % 19, chunk = i0 / 19;    // 19 k-blocks x 8 chunks
        for (int i = tid; i < B_ * TCH; i += 256) {
            int b = i / TCH, tt = i % TCH;
            int t = chunk * TCH + tt;
            mfS[b][tt] = (t < T_) ? mf[b * T_ + t] : 0.f;
        }
        __syncthreads();
        int k = kb * 256 + tid;
        float2 r2 = rot2t[k];
        float2 r = r2;
        {   // * rot304^chunk
            int e = chunk;
            float2 p = rot304t[k];
            while (e) { if (e & 1) r = cmul(r, p); p = cmul(p, p); e >>= 1; }
        }
        float s2a[B_], c2a[B_];
#pragma unroll
        for (int b = 0; b < B_; b++) { s2a[b] = 0.f; c2a[b] = 0.f; }
        for (int tt = 0; tt < TCH; tt++) {
            float sv = r.y, cv = r.x;
#pragma unroll
            for (int b = 0; b < B_; b++) {
                float m = mfS[b][tt];        // uniform address -> broadcast
                s2a[b] = fmaf(m, sv, s2a[b]);
                c2a[b] = fmaf(m, cv, c2a[b]);
            }
            r = cmul(r, r2);
        }
#pragma unroll
        for (int b = 0; b < B_; b++) {
            partS[(size_t)(chunk * 8 + b) * KP + k] = s2a[b];
            partC[(size_t)(chunk * 8 + b) * KP + k] = c2a[b];
        }
        return;
    }
    // basisD: Z[k2][t], ZT[t][k2], 64k x 64t tiles
    {
        int i0 = bx - 472;                    // 0..1519
        int kb = i0 / 20, tb = i0 % 20;
        int k0 = kb * 64, t0 = tb * 64;
        int kk = tid >> 2, tq = tid & 3;
        int k = k0 + kk;
        float2 r1 = rot1t[k];
        float2 acc = r1;                      // angle w*1
        {   // * rot8^tq
            float2 p = rot8t[k];
            if (tq & 1) acc = cmul(acc, p);
            p = cmul(p, p);
            if (tq & 2) acc = cmul(acc, p);
        }
        {   // * rot64^tb
            int e = tb;
            float2 p = rot64t[k];
            while (e) { if (e & 1) acc = cmul(acc, p); p = cmul(p, p); e >>= 1; }
        }
        bool kv = (k < K);
        float2 r32 = rot32t[k];
#pragma unroll
        for (int j = 0; j < 2; j++) {
            float2 r = acc;
            H8 hc, hs;
#pragma unroll
            for (int d = 0; d < 8; d++) {
                int tl = tq * 8 + j * 32 + d;
                bool ok = kv && (t0 + tl < T_);
                float c = ok ? r.x : 0.f, s = ok ? r.y : 0.f;
                hc.e[d] = (_Float16)c; hs.e[d] = (_Float16)s;
                HP pk; pk.hh[0] = hc.e[d]; pk.hh[1] = hs.e[d];
                *(unsigned*)&sZT[tl * 136 + 2 * kk] = pk.u;
                r = cmul(r, r1);
            }
            int ch = tq + 4 * j;              // chunk 0..7
            int rc = 2 * kk, rs = 2 * kk + 1;
            *(float4*)&sZ[rc * 80 + ((ch ^ (rc & 7)) << 3)] = hc.v;
            *(float4*)&sZ[rs * 80 + ((ch ^ (rs & 7)) << 3)] = hs.v;
            acc = cmul(acc, r32);
        }
        __syncthreads();
        // Z out: 128 rows x 128B
        {
            int c8 = tid & 7, rr = tid >> 3;  // rr 0..31
#pragma unroll
            for (int p = 0; p < 4; p++) {
                int row = p * 32 + rr;
                float4 v = *(const float4*)&sZ[row * 80 + ((c8 ^ (row & 7)) << 3)];
                *(float4*)&Zb[(size_t)(2 * k0 + row) * TP2 + t0 + c8 * 8] = v;
            }
        }
        // ZT out: 64 rows x 256B
        {
            int c16 = tid & 15, rr = tid >> 4; // rr 0..15
#pragma unroll
            for (int p = 0; p < 4; p++) {
                int row = p * 16 + rr;
                float4 v = *(const float4*)&sZT[row * 136 + c16 * 8];
                *(float4*)&ZT[(size_t)(t0 + row) * K2P + 2 * k0 + c16 * 8] = v;
            }
        }
    }
}

// ---------------- phi ----------------
__global__ __launch_bounds__(256) void phi_kernel(
    const float* __restrict__ partS, const float* __restrict__ partC,
    const float* __restrict__ cnt,
    float* __restrict__ cphi, float* __restrict__ sphi,
    float* __restrict__ rdcv, float* __restrict__ rdsv) {
    int k = blockIdx.x * 256 + threadIdx.x;   // 19 blocks
#pragma unroll
    for (int b = 0; b < B_; b++) {
        float s2 = 0.f, c2 = 0.f;
#pragma unroll
        for (int c = 0; c < 8; c++) {
            s2 += partS[(size_t)(c * 8 + b) * KP + k];
            c2 += partC[(size_t)(c * 8 + b) * KP + k];
        }
        float phi = 0.5f * atan2f(s2, c2);
        float cp = cosf(phi), sp = sinf(phi);
        float cn = cnt[b];
        float A = 0.5f * (cn + c2), D = 0.5f * (cn - c2), E = 0.5f * s2;
        int kidx = b * KP + k;
        cphi[kidx] = cp; sphi[kidx] = sp;
        rdcv[kidx] = 1.f / (cp * cp * A + 2.f * cp * sp * E + sp * sp * D);
        rdsv[kidx] = 1.f / (sp * sp * A - 2.f * cp * sp * E + cp * cp * D);
    }
}

// ---------------- 256-thread 128x128 MFMA core, counted-vmcnt depth-2 pipeline ----------------
#define KSTEP(LA, LB)                                                          \
    _Pragma("unroll")                                                          \
    for (int kc = 0; kc < 4; kc++) {                                           \
        int c = kc * 2 + kg;                                                   \
        h8 a0 = *(const h8*)((LA) + ((r0 * 8 + (c ^ x)) << 4));                \
        h8 a1 = *(const h8*)((LA) + (((r0 + 32) * 8 + (c ^ x)) << 4));         \
        h8 b0 = *(const h8*)((LB) + ((q0 * 8 + (c ^ x)) << 4));                \
        h8 b1 = *(const h8*)((LB) + (((q0 + 32) * 8 + (c ^ x)) << 4));         \
        acc00 = MFMA32(a0, b0, acc00);                                         \
        acc01 = MFMA32(a0, b1, acc01);                                         \
        acc10 = MFMA32(a1, b0, acc10);                                         \
        acc11 = MFMA32(a1, b1, acc11);                                         \
    }

// STAGEP: issue this thread's 8 async loads (4 A + 4 B) for K-step STEP into buffer BUF.
// Per wave = 8 vm instructions -> vmcnt counted in units of 8.
#define STAGEP(BUF, STEP) do {                                                 \
        char* Ld_ = ldsb + (BUF) * 32768;                                      \
        int rc_ = (STEP) << 7;                                                 \
        _Pragma("unroll")                                                      \
        for (int i_ = 0; i_ < 4; i_++)                                         \
            gload16(pA + rc_ + sA[i_], Ld_ + sL[i_]);                          \
        _Pragma("unroll")                                                      \
        for (int i_ = 0; i_ < 4; i_++)                                         \
            gload16(pB + rc_ + sA[i_], Ld_ + 16384 + sL[i_]);                  \
    } while (0)

// Pipeline invariants (depth-2, 2 buffers):
//  - entering step s: stage(s) [8/wave] + stage(s+1) [8/wave] in flight
//  - vmcnt(8): own stage(s) loads done; s_barrier: everyone's done  -> RAW safe
//  - KSTEP reads are consumed by MFMAs (compiler lgkmcnt) + explicit lgkmcnt(0)
//    before barrier #2 -> all reads complete before re-stage          -> WAR safe
#define GEMM_PIPE(NS)                                                          \
    STAGEP(0, 0);                                                              \
    STAGEP(1, 1);                                                              \
    int cur = 0;                                                               \
    for (int s = 0; s < (NS); s++) {                                           \
        if (s + 1 < (NS)) { asm volatile("s_waitcnt vmcnt(8)" ::: "memory"); } \
        else              { asm volatile("s_waitcnt vmcnt(0)" ::: "memory"); } \
        __builtin_amdgcn_s_barrier();                                          \
        const char* LA = ldsb + cur * 32768;                                   \
        const char* LB = LA + 16384;                                           \
        KSTEP(LA, LB);                                                         \
        asm volatile("s_waitcnt lgkmcnt(0)" ::: "memory");                     \
        __builtin_amdgcn_sched_barrier(0);                                     \
        __builtin_amdgcn_s_barrier();                                          \
        if (s + 2 < (NS)) STAGEP(cur, s + 2);                                  \
        cur ^= 1;                                                              \
    }

// ---------------- GEMM1: W[m][k2] = sum_t dm[m][t] * Z[k2][t], fused LS-combine ----------------
__global__ __launch_bounds__(256, 2) void gemm1x(
    const _Float16* __restrict__ dm, const _Float16* __restrict__ Zb,
    const float* __restrict__ cphi, const float* __restrict__ sphi,
    const float* __restrict__ rdc, const float* __restrict__ rds,
    _Float16* __restrict__ Wout) {
    __shared__ _Float16 lds[32768];   // 64KB: 2 bufs x (A 16KB | B 16KB)
    char* ldsb = (char*)lds;
    int bx = blockIdx.x;                    // 304 = 8 XCD * 38
    int g = (bx & 7) * 38 + (bx >> 3);      // bijective, XCD-chunked
    int mt = g & 3, nt = g >> 2;
    int m0 = mt * 128, n0 = nt * 128;
    int tid = threadIdx.x, lane = tid & 63, wv = tid >> 6;
    int ra = lane & 31, kg = lane >> 5, x = ra & 7;
    int wm = (wv & 1) * 64, wn = (wv >> 1) * 64;
    int r0 = wm + ra, q0 = wn + ra;
    f32x16 acc00 = Z16v, acc01 = Z16v, acc10 = Z16v, acc11 = Z16v;
    int sA[4], sL[4];
#pragma unroll
    for (int i = 0; i < 4; i++) {
        int g8 = i * 256 + tid;
        int r = g8 >> 3, c = g8 & 7;
        sA[i] = r * 2560 + ((c ^ (r & 7)) << 4);
        sL[i] = g8 << 4;
    }
    const char* pA = (const char*)dm + (size_t)m0 * 2560;
    const char* pB = (const char*)Zb + (size_t)n0 * 2560;
    GEMM_PIPE(NST1)
    // epilogue: Lomb-Scargle combine in-register (P,Q in adjacent lanes), write f16 W
    int bb = (m0 + wm) >> 6;
    int colk = lane & 31, rb4 = (lane >> 5) * 4;
#define EPI1(ACC, I, J) {                                                      \
        int k2 = n0 + wn + 32 * (J) + colk;                                    \
        int kidx = bb * KP + (k2 >> 1);                                        \
        float cp = cphi[kidx], sp = sphi[kidx];                                \
        float rc_ = rdc[kidx], rs_ = rds[kidx];                                \
        int par = k2 & 1;                                                      \
        _Pragma("unroll")                                                      \
        for (int reg = 0; reg < 16; reg++) {                                   \
            float own = (ACC)[reg];                                            \
            float oth = __shfl_xor(own, 1);                                    \
            float p = par ? oth : own, q = par ? own : oth;                    \
            float cc = (cp * p + sp * q) * rc_;                                \
            float sc = (cp * q - sp * p) * rs_;                                \
            float val = par ? (sp * cc + cp * sc) : (cp * cc - sp * sc);       \
            int row = m0 + wm + 32 * (I) + rb4 + (reg & 3) + 8 * (reg >> 2);   \
            Wout[(size_t)row * K2P + k2] = (_Float16)val;                      \
        } }
    EPI1(acc00, 0, 0); EPI1(acc01, 0, 1); EPI1(acc10, 1, 0); EPI1(acc11, 1, 1);
#undef EPI1
}

// ---------------- GEMM2: rpart[sk][m][t] = sum_{k2 in chunk} W[m][k2] * ZT[t][k2] ----------------
__global__ __launch_bounds__(256, 2) void gemm2x(
    const _Float16* __restrict__ Wm, const _Float16* __restrict__ ZT,
    float* __restrict__ rpart) {
    __shared__ _Float16 lds[32768];
    char* ldsb = (char*)lds;
    int bx = blockIdx.x;                 // 320 = 8 XCD * 40; one sk per XCD
    int sk = bx & 7;
    int idx = bx >> 3;                   // 0..39
    int nt = idx >> 2, mt = idx & 3;
    int m0 = mt * 128, t0 = nt * 128;
    int tid = threadIdx.x, lane = tid & 63, wv = tid >> 6;
    int ra = lane & 31, kg = lane >> 5, x = ra & 7;
    int wm = (wv & 1) * 64, wn = (wv >> 1) * 64;
    int r0 = wm + ra, q0 = wn + ra;
    f32x16 acc00 = Z16v, acc01 = Z16v, acc10 = Z16v, acc11 = Z16v;
    int sA[4], sL[4];
#pragma unroll
    for (int i = 0; i < 4; i++) {
        int g8 = i * 256 + tid;
        int r = g8 >> 3, c = g8 & 7;
        sA[i] = r * 19456 + ((c ^ (r & 7)) << 4);
        sL[i] = g8 << 4;
    }
    const char* pA = (const char*)Wm + (size_t)m0 * 19456 + sk * 2432;
    const char* pB = (const char*)ZT + (size_t)t0 * 19456 + sk * 2432;
    GEMM_PIPE(NST2)
    int colk = lane & 31, rb4 = (lane >> 5) * 4;
#define EPI2(ACC, I, J) {                                                      \
        int t = t0 + wn + 32 * (J) + colk;                                     \
        _Pragma("unroll")                                                      \
        for (int reg = 0; reg < 16; reg++) {                                   \
            int row = m0 + wm + 32 * (I) + rb4 + (reg & 3) + 8 * (reg >> 2);   \
            rpart[(size_t)(sk * M_ + row) * TP2 + t] = (ACC)[reg];             \
        } }
    EPI2(acc00, 0, 0); EPI2(acc01, 0, 1); EPI2(acc10, 1, 0); EPI2(acc11, 1, 1);
#undef EPI2
}

// ---------------- normalize + select ----------------
__global__ __launch_bounds__(256) void norm3_kernel(
    const float* __restrict__ rpart, const float* __restrict__ data,
    const float* __restrict__ mf, const float* __restrict__ cnt,
    float* __restrict__ out) {
    __shared__ float rsum[T_];
    __shared__ float4 red4[256];
    __shared__ float s_scale;
    int bc = blockIdx.x, b = bc >> 6;
    const size_t rbase = (size_t)bc * TP2;
    const size_t dbase = (size_t)bc * T_;
    const size_t rstr = (size_t)M_ * TP2;
    float sr = 0.f, srr = 0.f, sd = 0.f, sdd = 0.f;
    for (int t = threadIdx.x; t < T_; t += 256) {
        float r = 0.f;
#pragma unroll
        for (int s = 0; s < SPLITK; s++) r += rpart[s * rstr + rbase + t];
        rsum[t] = r;
        float m = mf[b * T_ + t];
        float xv = data[dbase + t];
        sr += r; srr += r * r; sd += xv * m; sdd += xv * xv * m;
    }
    red4[threadIdx.x] = make_float4(sr, srr, sd, sdd);
    __syncthreads();
    for (int w = 128; w > 0; w >>= 1) {
        if (threadIdx.x < w) {
            float4 a = red4[threadIdx.x], c = red4[threadIdx.x + w];
            red4[threadIdx.x] = make_float4(a.x + c.x, a.y + c.y, a.z + c.z, a.w + c.w);
        }
        __syncthreads();
    }
    if (threadIdx.x == 0) {
        float4 v = red4[0];
        float cn = cnt[b];
        float varr = (v.y - v.x * v.x / (float)T_) / (float)(T_ - 1);
        float vard = (v.w - v.z * v.z / cn) / (cn - 1.f);
        s_scale = sqrtf(vard / varr);
    }
    __syncthreads();
    float scale = s_scale;
    for (int t = threadIdx.x; t < T_; t += 256) {
        float m = mf[b * T_ + t];
        out[dbase + t] = (m > 0.5f) ? data[dbase + t] : rsum[t] * scale;
    }
}

extern "C" void kernel_launch(void* const* d_in, const int* in_sizes, int n_in,
                              void* d_out, int out_size, void* d_ws, size_t ws_size,
                              hipStream_t stream) {
    const float* data = (const float*)d_in[0];
    const void* mask = d_in[1];
    float* out = (float*)d_out;

    // Replicate numpy arange length computation exactly (double precision).
    const double timespan = 1.0 * (T_ + 1) - 1.0;               // 1200
    const double fstep = 1.0 / (timespan * 8.0);                // OSFREQ = 8
    const double stop = (1.0 * (double)T_) / (2.0 * timespan) + fstep;
    const int K = (int)ceil((stop - fstep) / fstep);            // 4800 (or 4801)

    char* w = (char*)d_ws;
    auto alloc = [&](size_t nbytes) {
        char* p = w;
        w += ((nbytes + 255) / 256) * 256;
        return p;
    };
    float*     mf    = (float*)    alloc((size_t)B_ * T_ * 4);
    float*     cnt   = (float*)    alloc(B_ * 4);
    float2*    rot1  = (float2*)   alloc((size_t)KP * 8);
    float2*    rot8  = (float2*)   alloc((size_t)KP * 8);
    float2*    rot32 = (float2*)   alloc((size_t)KP * 8);
    float2*    rot64 = (float2*)   alloc((size_t)KP * 8);
    float2*    rot2  = (float2*)   alloc((size_t)KP * 8);
    float2*    rot304= (float2*)   alloc((size_t)KP * 8);
    float*     partS = (float*)    alloc((size_t)64 * KP * 4);
    float*     partC = (float*)    alloc((size_t)64 * KP * 4);
    float*     cphi  = (float*)    alloc((size_t)B_ * KP * 4);
    float*     sphi  = (float*)    alloc((size_t)B_ * KP * 4);
    float*     rdc   = (float*)    alloc((size_t)B_ * KP * 4);
    float*     rds   = (float*)    alloc((size_t)B_ * KP * 4);
    _Float16*  dm_h  = (_Float16*) alloc((size_t)M_ * TP2 * 2);
    _Float16*  Z     = (_Float16*) alloc((size_t)K2P * TP2 * 2);
    _Float16*  ZT    = (_Float16*) alloc((size_t)TP2 * K2P * 2);
    _Float16*  W     = (_Float16*) alloc((size_t)M_ * K2P * 2);
    float*     rpart = (float*)    alloc((size_t)SPLITK * M_ * TP2 * 4);
    (void)ws_size; (void)in_sizes; (void)n_in; (void)out_size;

    seed_kernel<<<125, 256, 0, stream>>>(mask, mf, cnt, rot1, rot8, rot32,
                                         rot64, rot2, rot304, fstep);
    prep2_kernel<<<1992, 256, 0, stream>>>(data, mf, rot1, rot8, rot32, rot64,
                                           rot2, rot304, dm_h, partS, partC, Z, ZT, K);
    phi_kernel<<<19, 256, 0, stream>>>(partS, partC, cnt, cphi, sphi, rdc, rds);
    gemm1x<<<304, 256, 0, stream>>>(dm_h, Z, cphi, sphi, rdc, rds, W);
    gemm2x<<<320, 256, 0, stream>>>(W, ZT, rpart);
    norm3_kernel<<<M_, 256, 0, stream>>>(rpart, data, mf, cnt, out);
}

// Round 14
// 89.633 us; speedup vs baseline: 1.1220x; 1.1220x over previous
//
#include <hip/hip_runtime.h>
#include <math.h>

#define B_ 8
#define C_ 64
#define M_ 512            // B_*C_
#define T_ 1200
#define TP2 1280          // T padded to 128
#define KP 4864           // K padded (K = 4800)
#define K2P 9728          // 2*KP interleaved cos/sin
#define SPLITK 8
#define KCH 1216          // K2P/SPLITK halves
#define NST1 20           // TP2/64 reduction steps (gemm1)
#define NST2 19           // KCH/64 reduction steps (gemm2)
#define TCH 152           // tau t-chunk length (8*152 = 1216)

#ifndef M_PI
#define M_PI 3.14159265358979323846
#endif

typedef _Float16 h8 __attribute__((ext_vector_type(8)));
typedef float f32x16 __attribute__((ext_vector_type(16)));
union H8 { h8 h; float4 v; _Float16 e[8]; };
union HP { _Float16 hh[2]; unsigned u; };
union F4U { float4 v; float f[4]; };

#define Z16v {0.f,0.f,0.f,0.f,0.f,0.f,0.f,0.f,0.f,0.f,0.f,0.f,0.f,0.f,0.f,0.f}
#define MFMA32(a, b, c) __builtin_amdgcn_mfma_f32_32x32x16_f16(a, b, c, 0, 0, 0)

__device__ __forceinline__ float2 cmul(float2 a, float2 b) {
    return make_float2(a.x * b.x - a.y * b.y, a.y * b.x + a.x * b.y);
}

// async global->LDS, 16B per lane (dest resolves to wave base + lane*16)
__device__ __forceinline__ void gload16(const void* g, void* l) {
    __builtin_amdgcn_global_load_lds(
        (const __attribute__((address_space(1))) unsigned int*)g,
        (__attribute__((address_space(3))) unsigned int*)l, 16, 0, 0);
}

__device__ int detect_mode(const void* mask_raw) {
    __shared__ int sb0, sb1;
    if (threadIdx.x == 0) { sb0 = 0; sb1 = 0; }
    __syncthreads();
    const unsigned* wi = (const unsigned*)mask_raw;
    const float* wf = (const float*)mask_raw;
    int nw = (B_ * T_) >> 2;
    int badI = 0, badF = 0;
    for (int i = threadIdx.x; i < nw; i += blockDim.x) {
        unsigned v = wi[i];
        badI |= (v > 1u);
        float f = wf[i];
        badF |= !(f == 0.0f || f == 1.0f);
    }
    if (badI) sb0 = 1;
    if (badF) sb1 = 1;
    __syncthreads();
    return (!sb0) ? 0 : ((!sb1) ? 1 : 2);
}

__device__ __forceinline__ float mval(const void* mask_raw, int mode, int idx) {
    if (mode == 0) return (float)((const int*)mask_raw)[idx];
    if (mode == 1) return ((const float*)mask_raw)[idx];
    return (float)((const unsigned char*)mask_raw)[idx];
}

// ---------------- K1 seed: rot tables (0..113) | mf (114..123) | cnt (124) ----------------
__global__ __launch_bounds__(256) void seed_kernel(
    const void* __restrict__ mask, float* __restrict__ mf, float* __restrict__ cnt,
    float2* __restrict__ rot1, float2* __restrict__ rot8,
    float2* __restrict__ rot32, float2* __restrict__ rot64,
    float2* __restrict__ rot2, float2* __restrict__ rot304, double fstep) {
    int bx = blockIdx.x, tid = threadIdx.x;
    if (bx < 114) {
        int tb = bx / 19;
        int k = (bx % 19) * 256 + tid;     // < 4864
        double om = 2.0 * M_PI * (fstep + (double)k * fstep);
        double w = (double)((float)om);    // reference rounds omega to f32
        double mult = (tb == 0) ? 1.0 : (tb == 1) ? 8.0 : (tb == 2) ? 32.0
                    : (tb == 3) ? 64.0 : (tb == 4) ? 2.0 : 304.0;
        double s, c;
        sincos(mult * w, &s, &c);
        float2 v = make_float2((float)c, (float)s);
        if (tb == 0)      rot1[k] = v;
        else if (tb == 1) rot8[k] = v;
        else if (tb == 2) rot32[k] = v;
        else if (tb == 3) rot64[k] = v;
        else if (tb == 4) rot2[k] = v;
        else              rot304[k] = v;
        return;
    }
    int mode = detect_mode(mask);
    if (bx < 124) {
        // mf convert, vectorized
        int i = ((bx - 114) * 256 + tid) * 4;   // 10 blocks cover 9600
        if (i >= B_ * T_) return;
        F4U o;
        if (mode == 0) {
            int4 v = *(const int4*)((const int*)mask + i);
            o.f[0] = (float)v.x; o.f[1] = (float)v.y; o.f[2] = (float)v.z; o.f[3] = (float)v.w;
        } else if (mode == 1) {
            o.v = *(const float4*)((const float*)mask + i);
        } else {
            unsigned v = *(const unsigned*)((const unsigned char*)mask + i);
            o.f[0] = (float)(v & 0xff); o.f[1] = (float)((v >> 8) & 0xff);
            o.f[2] = (float)((v >> 16) & 0xff); o.f[3] = (float)((v >> 24) & 0xff);
        }
        *(float4*)&mf[i] = o.v;
        return;
    }
    // bx == 124: cnt via per-b block reduction over raw mask (no atomics)
    {
        __shared__ float red[256];
        for (int b = 0; b < B_; b++) {
            float s = 0.f;
            for (int t = tid; t < T_; t += 256) s += mval(mask, mode, b * T_ + t);
            red[tid] = s; __syncthreads();
            for (int w = 128; w > 0; w >>= 1) {
                if (tid < w) red[tid] += red[tid + w];
                __syncthreads();
            }
            if (tid == 0) cnt[b] = red[0];
            __syncthreads();
        }
    }
}

// ---------------- K2 prep2: dm (0..319) | tau (320..471) | basisD (472..1991) ----------------
__global__ __launch_bounds__(256) void prep2_kernel(
    const float* __restrict__ data, const float* __restrict__ mf,
    const float2* __restrict__ rot1t, const float2* __restrict__ rot8t,
    const float2* __restrict__ rot32t, const float2* __restrict__ rot64t,
    const float2* __restrict__ rot2t, const float2* __restrict__ rot304t,
    _Float16* __restrict__ dm, float* __restrict__ partS, float* __restrict__ partC,
    _Float16* __restrict__ Zb, _Float16* __restrict__ ZT, int K) {
    __shared__ float mfS[B_][TCH];            // tau role
    __shared__ _Float16 sZ[128 * 80];         // basisD role
    __shared__ _Float16 sZT[64 * 136];        // basisD role
    int bx = blockIdx.x, tid = threadIdx.x;
    if (bx < 320) {
        // dm: dm[bc][TP2] = f16(data*mf), 8 halves/thread
        int base = (bx * 256 + tid) * 8;
        int t = base % TP2, bc = base / TP2;
        H8 o;
        if (t < T_) {
            int b = bc >> 6;
            F4U d0, d1, m0, m1;
            d0.v = *(const float4*)&data[bc * T_ + t];
            d1.v = *(const float4*)&data[bc * T_ + t + 4];
            m0.v = *(const float4*)&mf[b * T_ + t];
            m1.v = *(const float4*)&mf[b * T_ + t + 4];
#pragma unroll
            for (int e = 0; e < 4; e++) {
                o.e[e]     = (_Float16)(d0.f[e] * m0.f[e]);
                o.e[e + 4] = (_Float16)(d1.f[e] * m1.f[e]);
            }
        } else {
#pragma unroll
            for (int e = 0; e < 8; e++) o.e[e] = (_Float16)0.f;
        }
        *(float4*)&dm[base] = o.v;
        return;
    }
    if (bx < 472) {
        // tau partials
        int i0 = bx - 320;                    // 0..151
        int kb = i0 % 19, chunk = i0 / 19;    // 19 k-blocks x 8 chunks
        for (int i = tid; i < B_ * TCH; i += 256) {
            int b = i / TCH, tt = i % TCH;
            int t = chunk * TCH + tt;
            mfS[b][tt] = (t < T_) ? mf[b * T_ + t] : 0.f;
        }
        __syncthreads();
        int k = kb * 256 + tid;
        float2 r2 = rot2t[k];
        float2 r = r2;
        {   // * rot304^chunk
            int e = chunk;
            float2 p = rot304t[k];
            while (e) { if (e & 1) r = cmul(r, p); p = cmul(p, p); e >>= 1; }
        }
        float s2a[B_], c2a[B_];
#pragma unroll
        for (int b = 0; b < B_; b++) { s2a[b] = 0.f; c2a[b] = 0.f; }
        for (int tt = 0; tt < TCH; tt++) {
            float sv = r.y, cv = r.x;
#pragma unroll
            for (int b = 0; b < B_; b++) {
                float m = mfS[b][tt];        // uniform address -> broadcast
                s2a[b] = fmaf(m, sv, s2a[b]);
                c2a[b] = fmaf(m, cv, c2a[b]);
            }
            r = cmul(r, r2);
        }
#pragma unroll
        for (int b = 0; b < B_; b++) {
            partS[(size_t)(chunk * 8 + b) * KP + k] = s2a[b];
            partC[(size_t)(chunk * 8 + b) * KP + k] = c2a[b];
        }
        return;
    }
    // basisD: Z[k2][t], ZT[t][k2], 64k x 64t tiles
    {
        int i0 = bx - 472;                    // 0..1519
        int kb = i0 / 20, tb = i0 % 20;
        int k0 = kb * 64, t0 = tb * 64;
        int kk = tid >> 2, tq = tid & 3;
        int k = k0 + kk;
        float2 r1 = rot1t[k];
        float2 acc = r1;                      // angle w*1
        {   // * rot8^tq
            float2 p = rot8t[k];
            if (tq & 1) acc = cmul(acc, p);
            p = cmul(p, p);
            if (tq & 2) acc = cmul(acc, p);
        }
        {   // * rot64^tb
            int e = tb;
            float2 p = rot64t[k];
            while (e) { if (e & 1) acc = cmul(acc, p); p = cmul(p, p); e >>= 1; }
        }
        bool kv = (k < K);
        float2 r32 = rot32t[k];
#pragma unroll
        for (int j = 0; j < 2; j++) {
            float2 r = acc;
            H8 hc, hs;
#pragma unroll
            for (int d = 0; d < 8; d++) {
                int tl = tq * 8 + j * 32 + d;
                bool ok = kv && (t0 + tl < T_);
                float c = ok ? r.x : 0.f, s = ok ? r.y : 0.f;
                hc.e[d] = (_Float16)c; hs.e[d] = (_Float16)s;
                HP pk; pk.hh[0] = hc.e[d]; pk.hh[1] = hs.e[d];
                *(unsigned*)&sZT[tl * 136 + 2 * kk] = pk.u;
                r = cmul(r, r1);
            }
            int ch = tq + 4 * j;              // chunk 0..7
            int rc = 2 * kk, rs = 2 * kk + 1;
            *(float4*)&sZ[rc * 80 + ((ch ^ (rc & 7)) << 3)] = hc.v;
            *(float4*)&sZ[rs * 80 + ((ch ^ (rs & 7)) << 3)] = hs.v;
            acc = cmul(acc, r32);
        }
        __syncthreads();
        // Z out: 128 rows x 128B
        {
            int c8 = tid & 7, rr = tid >> 3;  // rr 0..31
#pragma unroll
            for (int p = 0; p < 4; p++) {
                int row = p * 32 + rr;
                float4 v = *(const float4*)&sZ[row * 80 + ((c8 ^ (row & 7)) << 3)];
                *(float4*)&Zb[(size_t)(2 * k0 + row) * TP2 + t0 + c8 * 8] = v;
            }
        }
        // ZT out: 64 rows x 256B
        {
            int c16 = tid & 15, rr = tid >> 4; // rr 0..15
#pragma unroll
            for (int p = 0; p < 4; p++) {
                int row = p * 16 + rr;
                float4 v = *(const float4*)&sZT[row * 136 + c16 * 8];
                *(float4*)&ZT[(size_t)(t0 + row) * K2P + 2 * k0 + c16 * 8] = v;
            }
        }
    }
}

// ---------------- 256-thread 128x128 MFMA core (R12 structure) ----------------
#define KSTEP(LA, LB)                                                          \
    _Pragma("unroll")                                                          \
    for (int kc = 0; kc < 4; kc++) {                                           \
        int c = kc * 2 + kg;                                                   \
        h8 a0 = *(const h8*)((LA) + ((r0 * 8 + (c ^ x)) << 4));                \
        h8 a1 = *(const h8*)((LA) + (((r0 + 32) * 8 + (c ^ x)) << 4));         \
        h8 b0 = *(const h8*)((LB) + ((q0 * 8 + (c ^ x)) << 4));                \
        h8 b1 = *(const h8*)((LB) + (((q0 + 32) * 8 + (c ^ x)) << 4));         \
        acc00 = MFMA32(a0, b0, acc00);                                         \
        acc01 = MFMA32(a0, b1, acc01);                                         \
        acc10 = MFMA32(a1, b0, acc10);                                         \
        acc11 = MFMA32(a1, b1, acc11);                                         \
    }

// ---------------- GEMM1: W[m][k2] = sum_t dm[m][t]*Z[k2][t], fused phi + LS-combine ----------------
__global__ __launch_bounds__(256, 2) void gemm1x(
    const _Float16* __restrict__ dm, const _Float16* __restrict__ Zb,
    const float* __restrict__ partS, const float* __restrict__ partC,
    const float* __restrict__ cnt,
    _Float16* __restrict__ Wout) {
    __shared__ _Float16 lds[32768];   // 64KB: 2 bufs x (A 16KB | B 16KB)
    char* ldsb = (char*)lds;
    int bx = blockIdx.x;                    // 304 = 8 XCD * 38
    int g = (bx & 7) * 38 + (bx >> 3);      // bijective, XCD-chunked
    int mt = g & 3, nt = g >> 2;
    int m0 = mt * 128, n0 = nt * 128;
    int tid = threadIdx.x, lane = tid & 63, wv = tid >> 6;
    int ra = lane & 31, kg = lane >> 5, x = ra & 7;
    int wm = (wv & 1) * 64, wn = (wv >> 1) * 64;
    int r0 = wm + ra, q0 = wn + ra;
    f32x16 acc00 = Z16v, acc01 = Z16v, acc10 = Z16v, acc11 = Z16v;
    int sA[4], sL[4];
#pragma unroll
    for (int i = 0; i < 4; i++) {
        int g8 = i * 256 + tid;
        int r = g8 >> 3, c = g8 & 7;
        sA[i] = r * 2560 + ((c ^ (r & 7)) << 4);
        sL[i] = g8 << 4;
    }
    const char* pA = (const char*)dm + (size_t)m0 * 2560;
    const char* pB = (const char*)Zb + (size_t)n0 * 2560;
#pragma unroll
    for (int i = 0; i < 4; i++) gload16(pA + sA[i], ldsb + sL[i]);
#pragma unroll
    for (int i = 0; i < 4; i++) gload16(pB + sA[i], ldsb + 16384 + sL[i]);
    __syncthreads();
    int cur = 0;
    for (int step = 0; step < NST1; step++) {
        if (step + 1 < NST1) {
            int rc = (step + 1) << 7;
            char* lb = ldsb + (cur ^ 1) * 32768;
#pragma unroll
            for (int i = 0; i < 4; i++) gload16(pA + rc + sA[i], lb + sL[i]);
#pragma unroll
            for (int i = 0; i < 4; i++) gload16(pB + rc + sA[i], lb + 16384 + sL[i]);
        }
        const char* LA = ldsb + cur * 32768;
        const char* LB = LA + 16384;
        KSTEP(LA, LB);
        __syncthreads();
        cur ^= 1;
    }
    // epilogue: inline phi (same float math as the old phi_kernel) + LS-combine
    int bb = (m0 + wm) >> 6;
    int colk = lane & 31, rb4 = (lane >> 5) * 4;
    float cn = cnt[bb];
    float cpJ[2], spJ[2], rcJ[2], rsJ[2];
#pragma unroll
    for (int J = 0; J < 2; J++) {
        int k2 = n0 + wn + 32 * J + colk;
        int k = k2 >> 1;
        float s2 = 0.f, c2 = 0.f;
#pragma unroll
        for (int c = 0; c < 8; c++) {
            s2 += partS[(size_t)(c * 8 + bb) * KP + k];
            c2 += partC[(size_t)(c * 8 + bb) * KP + k];
        }
        float phi = 0.5f * atan2f(s2, c2);
        float cp = cosf(phi), sp = sinf(phi);
        float A = 0.5f * (cn + c2), D = 0.5f * (cn - c2), E = 0.5f * s2;
        cpJ[J] = cp; spJ[J] = sp;
        rcJ[J] = 1.f / (cp * cp * A + 2.f * cp * sp * E + sp * sp * D);
        rsJ[J] = 1.f / (sp * sp * A - 2.f * cp * sp * E + cp * cp * D);
    }
#define EPI1(ACC, I, J) {                                                      \
        int k2 = n0 + wn + 32 * (J) + colk;                                    \
        float cp = cpJ[J], sp = spJ[J];                                        \
        float rc_ = rcJ[J], rs_ = rsJ[J];                                      \
        int par = k2 & 1;                                                      \
        _Pragma("unroll")                                                      \
        for (int reg = 0; reg < 16; reg++) {                                   \
            float own = (ACC)[reg];                                            \
            float oth = __shfl_xor(own, 1);                                    \
            float p = par ? oth : own, q = par ? own : oth;                    \
            float cc = (cp * p + sp * q) * rc_;                                \
            float sc = (cp * q - sp * p) * rs_;                                \
            float val = par ? (sp * cc + cp * sc) : (cp * cc - sp * sc);       \
            int row = m0 + wm + 32 * (I) + rb4 + (reg & 3) + 8 * (reg >> 2);   \
            Wout[(size_t)row * K2P + k2] = (_Float16)val;                      \
        } }
    EPI1(acc00, 0, 0); EPI1(acc01, 0, 1); EPI1(acc10, 1, 0); EPI1(acc11, 1, 1);
#undef EPI1
}

// ---------------- GEMM2: rpart[sk][m][t] (f16) = sum_{k2 in chunk} W[m][k2] * ZT[t][k2] ----------------
__global__ __launch_bounds__(256, 2) void gemm2x(
    const _Float16* __restrict__ Wm, const _Float16* __restrict__ ZT,
    _Float16* __restrict__ rpart) {
    __shared__ _Float16 lds[32768];
    char* ldsb = (char*)lds;
    int bx = blockIdx.x;                 // 320 = 8 XCD * 40; one sk per XCD
    int sk = bx & 7;
    int idx = bx >> 3;                   // 0..39
    int nt = idx >> 2, mt = idx & 3;
    int m0 = mt * 128, t0 = nt * 128;
    int tid = threadIdx.x, lane = tid & 63, wv = tid >> 6;
    int ra = lane & 31, kg = lane >> 5, x = ra & 7;
    int wm = (wv & 1) * 64, wn = (wv >> 1) * 64;
    int r0 = wm + ra, q0 = wn + ra;
    f32x16 acc00 = Z16v, acc01 = Z16v, acc10 = Z16v, acc11 = Z16v;
    int sA[4], sL[4];
#pragma unroll
    for (int i = 0; i < 4; i++) {
        int g8 = i * 256 + tid;
        int r = g8 >> 3, c = g8 & 7;
        sA[i] = r * 19456 + ((c ^ (r & 7)) << 4);
        sL[i] = g8 << 4;
    }
    const char* pA = (const char*)Wm + (size_t)m0 * 19456 + sk * 2432;
    const char* pB = (const char*)ZT + (size_t)t0 * 19456 + sk * 2432;
#pragma unroll
    for (int i = 0; i < 4; i++) gload16(pA + sA[i], ldsb + sL[i]);
#pragma unroll
    for (int i = 0; i < 4; i++) gload16(pB + sA[i], ldsb + 16384 + sL[i]);
    __syncthreads();
    int cur = 0;
    for (int step = 0; step < NST2; step++) {
        if (step + 1 < NST2) {
            int rc = (step + 1) << 7;
            char* lb = ldsb + (cur ^ 1) * 32768;
#pragma unroll
            for (int i = 0; i < 4; i++) gload16(pA + rc + sA[i], lb + sL[i]);
#pragma unroll
            for (int i = 0; i < 4; i++) gload16(pB + rc + sA[i], lb + 16384 + sL[i]);
        }
        const char* LA = ldsb + cur * 32768;
        const char* LB = LA + 16384;
        KSTEP(LA, LB);
        __syncthreads();
        cur ^= 1;
    }
    int colk = lane & 31, rb4 = (lane >> 5) * 4;
#define EPI2(ACC, I, J) {                                                      \
        int t = t0 + wn + 32 * (J) + colk;                                     \
        _Pragma("unroll")                                                      \
        for (int reg = 0; reg < 16; reg++) {                                   \
            int row = m0 + wm + 32 * (I) + rb4 + (reg & 3) + 8 * (reg >> 2);   \
            rpart[(size_t)(sk * M_ + row) * TP2 + t] = (_Float16)(ACC)[reg];   \
        } }
    EPI2(acc00, 0, 0); EPI2(acc01, 0, 1); EPI2(acc10, 1, 0); EPI2(acc11, 1, 1);
#undef EPI2
}

// ---------------- normalize + select (f16 rpart) ----------------
__global__ __launch_bounds__(256) void norm3_kernel(
    const _Float16* __restrict__ rpart, const float* __restrict__ data,
    const float* __restrict__ mf, const float* __restrict__ cnt,
    float* __restrict__ out) {
    __shared__ float rsum[T_];
    __shared__ float4 red4[256];
    __shared__ float s_scale;
    int bc = blockIdx.x, b = bc >> 6;
    const size_t rbase = (size_t)bc * TP2;
    const size_t dbase = (size_t)bc * T_;
    const size_t rstr = (size_t)M_ * TP2;
    float sr = 0.f, srr = 0.f, sd = 0.f, sdd = 0.f;
    for (int t = threadIdx.x; t < T_; t += 256) {
        float r = 0.f;
#pragma unroll
        for (int s = 0; s < SPLITK; s++) r += (float)rpart[s * rstr + rbase + t];
        rsum[t] = r;
        float m = mf[b * T_ + t];
        float xv = data[dbase + t];
        sr += r; srr += r * r; sd += xv * m; sdd += xv * xv * m;
    }
    red4[threadIdx.x] = make_float4(sr, srr, sd, sdd);
    __syncthreads();
    for (int w = 128; w > 0; w >>= 1) {
        if (threadIdx.x < w) {
            float4 a = red4[threadIdx.x], c = red4[threadIdx.x + w];
            red4[threadIdx.x] = make_float4(a.x + c.x, a.y + c.y, a.z + c.z, a.w + c.w);
        }
        __syncthreads();
    }
    if (threadIdx.x == 0) {
        float4 v = red4[0];
        float cn = cnt[b];
        float varr = (v.y - v.x * v.x / (float)T_) / (float)(T_ - 1);
        float vard = (v.w - v.z * v.z / cn) / (cn - 1.f);
        s_scale = sqrtf(vard / varr);
    }
    __syncthreads();
    float scale = s_scale;
    for (int t = threadIdx.x; t < T_; t += 256) {
        float m = mf[b * T_ + t];
        out[dbase + t] = (m > 0.5f) ? data[dbase + t] : rsum[t] * scale;
    }
}

extern "C" void kernel_launch(void* const* d_in, const int* in_sizes, int n_in,
                              void* d_out, int out_size, void* d_ws, size_t ws_size,
                              hipStream_t stream) {
    const float* data = (const float*)d_in[0];
    const void* mask = d_in[1];
    float* out = (float*)d_out;

    // Replicate numpy arange length computation exactly (double precision).
    const double timespan = 1.0 * (T_ + 1) - 1.0;               // 1200
    const double fstep = 1.0 / (timespan * 8.0);                // OSFREQ = 8
    const double stop = (1.0 * (double)T_) / (2.0 * timespan) + fstep;
    const int K = (int)ceil((stop - fstep) / fstep);            // 4800 (or 4801)

    char* w = (char*)d_ws;
    auto alloc = [&](size_t nbytes) {
        char* p = w;
        w += ((nbytes + 255) / 256) * 256;
        return p;
    };
    float*     mf    = (float*)    alloc((size_t)B_ * T_ * 4);
    float*     cnt   = (float*)    alloc(B_ * 4);
    float2*    rot1  = (float2*)   alloc((size_t)KP * 8);
    float2*    rot8  = (float2*)   alloc((size_t)KP * 8);
    float2*    rot32 = (float2*)   alloc((size_t)KP * 8);
    float2*    rot64 = (float2*)   alloc((size_t)KP * 8);
    float2*    rot2  = (float2*)   alloc((size_t)KP * 8);
    float2*    rot304= (float2*)   alloc((size_t)KP * 8);
    float*     partS = (float*)    alloc((size_t)64 * KP * 4);
    float*     partC = (float*)    alloc((size_t)64 * KP * 4);
    _Float16*  dm_h  = (_Float16*) alloc((size_t)M_ * TP2 * 2);
    _Float16*  Z     = (_Float16*) alloc((size_t)K2P * TP2 * 2);
    _Float16*  ZT    = (_Float16*) alloc((size_t)TP2 * K2P * 2);
    _Float16*  W     = (_Float16*) alloc((size_t)M_ * K2P * 2);
    _Float16*  rpart = (_Float16*) alloc((size_t)SPLITK * M_ * TP2 * 2);
    (void)ws_size; (void)in_sizes; (void)n_in; (void)out_size;

    seed_kernel<<<125, 256, 0, stream>>>(mask, mf, cnt, rot1, rot8, rot32,
                                         rot64, rot2, rot304, fstep);
    prep2_kernel<<<1992, 256, 0, stream>>>(data, mf, rot1, rot8, rot32, rot64,
                                           rot2, rot304, dm_h, partS, partC, Z, ZT, K);
    gemm1x<<<304, 256, 0, stream>>>(dm_h, Z, partS, partC, cnt, W);
    gemm2x<<<320, 256, 0, stream>>>(W, ZT, rpart);
    norm3_kernel<<<M_, 256, 0, stream>>>(rpart, data, mf, cnt, out);
}

// Round 15
// 88.266 us; speedup vs baseline: 1.1394x; 1.0155x over previous
//
#include <hip/hip_runtime.h>
#include <math.h>

#define B_ 8
#define C_ 64
#define M_ 512            // B_*C_
#define T_ 1200
#define TP2 1280          // T padded to 128
#define KP 4864           // K padded (K = 4800)
#define K2P 9728          // 2*KP interleaved cos/sin
#define SPLITK 8
#define KCH 1216          // K2P/SPLITK halves
#define NST1 20           // TP2/64 reduction steps (gemm1)
#define NST2 19           // KCH/64 reduction steps (gemm2)
#define TCH 152           // tau t-chunk length (8*152 = 1216)

#ifndef M_PI
#define M_PI 3.14159265358979323846
#endif

typedef _Float16 h8 __attribute__((ext_vector_type(8)));
typedef float f32x16 __attribute__((ext_vector_type(16)));
union H8 { h8 h; float4 v; _Float16 e[8]; };
union HP { _Float16 hh[2]; unsigned u; };
union F4U { float4 v; float f[4]; };

#define Z16v {0.f,0.f,0.f,0.f,0.f,0.f,0.f,0.f,0.f,0.f,0.f,0.f,0.f,0.f,0.f,0.f}
#define MFMA32(a, b, c) __builtin_amdgcn_mfma_f32_32x32x16_f16(a, b, c, 0, 0, 0)

__device__ __forceinline__ float2 cmul(float2 a, float2 b) {
    return make_float2(a.x * b.x - a.y * b.y, a.y * b.x + a.x * b.y);
}

// async global->LDS, 16B per lane (dest resolves to wave base + lane*16)
__device__ __forceinline__ void gload16(const void* g, void* l) {
    __builtin_amdgcn_global_load_lds(
        (const __attribute__((address_space(1))) unsigned int*)g,
        (__attribute__((address_space(3))) unsigned int*)l, 16, 0, 0);
}

__device__ int detect_mode(const void* mask_raw) {
    __shared__ int sb0, sb1;
    if (threadIdx.x == 0) { sb0 = 0; sb1 = 0; }
    __syncthreads();
    const unsigned* wi = (const unsigned*)mask_raw;
    const float* wf = (const float*)mask_raw;
    int nw = (B_ * T_) >> 2;
    int badI = 0, badF = 0;
    for (int i = threadIdx.x; i < nw; i += blockDim.x) {
        unsigned v = wi[i];
        badI |= (v > 1u);
        float f = wf[i];
        badF |= !(f == 0.0f || f == 1.0f);
    }
    if (badI) sb0 = 1;
    if (badF) sb1 = 1;
    __syncthreads();
    return (!sb0) ? 0 : ((!sb1) ? 1 : 2);
}

__device__ __forceinline__ float mval(const void* mask_raw, int mode, int idx) {
    if (mode == 0) return (float)((const int*)mask_raw)[idx];
    if (mode == 1) return ((const float*)mask_raw)[idx];
    return (float)((const unsigned char*)mask_raw)[idx];
}

// ---------------- K1 seed: rot tables (0..113) | mf (114..123) | cnt (124) ----------------
__global__ __launch_bounds__(256) void seed_kernel(
    const void* __restrict__ mask, float* __restrict__ mf, float* __restrict__ cnt,
    float2* __restrict__ rot1, float2* __restrict__ rot8,
    float2* __restrict__ rot32, float2* __restrict__ rot64,
    float2* __restrict__ rot2, float2* __restrict__ rot304, double fstep) {
    int bx = blockIdx.x, tid = threadIdx.x;
    if (bx < 114) {
        int tb = bx / 19;
        int k = (bx % 19) * 256 + tid;     // < 4864
        double om = 2.0 * M_PI * (fstep + (double)k * fstep);
        double w = (double)((float)om);    // reference rounds omega to f32
        double mult = (tb == 0) ? 1.0 : (tb == 1) ? 8.0 : (tb == 2) ? 32.0
                    : (tb == 3) ? 64.0 : (tb == 4) ? 2.0 : 304.0;
        double s, c;
        sincos(mult * w, &s, &c);
        float2 v = make_float2((float)c, (float)s);
        if (tb == 0)      rot1[k] = v;
        else if (tb == 1) rot8[k] = v;
        else if (tb == 2) rot32[k] = v;
        else if (tb == 3) rot64[k] = v;
        else if (tb == 4) rot2[k] = v;
        else              rot304[k] = v;
        return;
    }
    int mode = detect_mode(mask);
    if (bx < 124) {
        // mf convert, vectorized
        int i = ((bx - 114) * 256 + tid) * 4;   // 10 blocks cover 9600
        if (i >= B_ * T_) return;
        F4U o;
        if (mode == 0) {
            int4 v = *(const int4*)((const int*)mask + i);
            o.f[0] = (float)v.x; o.f[1] = (float)v.y; o.f[2] = (float)v.z; o.f[3] = (float)v.w;
        } else if (mode == 1) {
            o.v = *(const float4*)((const float*)mask + i);
        } else {
            unsigned v = *(const unsigned*)((const unsigned char*)mask + i);
            o.f[0] = (float)(v & 0xff); o.f[1] = (float)((v >> 8) & 0xff);
            o.f[2] = (float)((v >> 16) & 0xff); o.f[3] = (float)((v >> 24) & 0xff);
        }
        *(float4*)&mf[i] = o.v;
        return;
    }
    // bx == 124: cnt via per-b block reduction over raw mask (no atomics)
    {
        __shared__ float red[256];
        for (int b = 0; b < B_; b++) {
            float s = 0.f;
            for (int t = tid; t < T_; t += 256) s += mval(mask, mode, b * T_ + t);
            red[tid] = s; __syncthreads();
            for (int w = 128; w > 0; w >>= 1) {
                if (tid < w) red[tid] += red[tid + w];
                __syncthreads();
            }
            if (tid == 0) cnt[b] = red[0];
            __syncthreads();
        }
    }
}

// ---------------- K2 prep2: dm (0..319) | tau (320..471) | basisD (472..1991) ----------------
__global__ __launch_bounds__(256) void prep2_kernel(
    const float* __restrict__ data, const float* __restrict__ mf,
    const float2* __restrict__ rot1t, const float2* __restrict__ rot8t,
    const float2* __restrict__ rot32t, const float2* __restrict__ rot64t,
    const float2* __restrict__ rot2t, const float2* __restrict__ rot304t,
    _Float16* __restrict__ dm, float* __restrict__ partS, float* __restrict__ partC,
    _Float16* __restrict__ Zb, _Float16* __restrict__ ZT, int K) {
    __shared__ float mfS[B_][TCH];            // tau role
    __shared__ _Float16 sZ[128 * 80];         // basisD role
    __shared__ _Float16 sZT[64 * 136];        // basisD role
    int bx = blockIdx.x, tid = threadIdx.x;
    if (bx < 320) {
        // dm: dm[bc][TP2] = f16(data*mf), 8 halves/thread
        int base = (bx * 256 + tid) * 8;
        int t = base % TP2, bc = base / TP2;
        H8 o;
        if (t < T_) {
            int b = bc >> 6;
            F4U d0, d1, m0, m1;
            d0.v = *(const float4*)&data[bc * T_ + t];
            d1.v = *(const float4*)&data[bc * T_ + t + 4];
            m0.v = *(const float4*)&mf[b * T_ + t];
            m1.v = *(const float4*)&mf[b * T_ + t + 4];
#pragma unroll
            for (int e = 0; e < 4; e++) {
                o.e[e]     = (_Float16)(d0.f[e] * m0.f[e]);
                o.e[e + 4] = (_Float16)(d1.f[e] * m1.f[e]);
            }
        } else {
#pragma unroll
            for (int e = 0; e < 8; e++) o.e[e] = (_Float16)0.f;
        }
        *(float4*)&dm[base] = o.v;
        return;
    }
    if (bx < 472) {
        // tau partials
        int i0 = bx - 320;                    // 0..151
        int kb = i0 % 19, chunk = i0 / 19;    // 19 k-blocks x 8 chunks
        for (int i = tid; i < B_ * TCH; i += 256) {
            int b = i / TCH, tt = i % TCH;
            int t = chunk * TCH + tt;
            mfS[b][tt] = (t < T_) ? mf[b * T_ + t] : 0.f;
        }
        __syncthreads();
        int k = kb * 256 + tid;
        float2 r2 = rot2t[k];
        float2 r = r2;
        {   // * rot304^chunk
            int e = chunk;
            float2 p = rot304t[k];
            while (e) { if (e & 1) r = cmul(r, p); p = cmul(p, p); e >>= 1; }
        }
        float s2a[B_], c2a[B_];
#pragma unroll
        for (int b = 0; b < B_; b++) { s2a[b] = 0.f; c2a[b] = 0.f; }
        for (int tt = 0; tt < TCH; tt++) {
            float sv = r.y, cv = r.x;
#pragma unroll
            for (int b = 0; b < B_; b++) {
                float m = mfS[b][tt];        // uniform address -> broadcast
                s2a[b] = fmaf(m, sv, s2a[b]);
                c2a[b] = fmaf(m, cv, c2a[b]);
            }
            r = cmul(r, r2);
        }
#pragma unroll
        for (int b = 0; b < B_; b++) {
            partS[(size_t)(chunk * 8 + b) * KP + k] = s2a[b];
            partC[(size_t)(chunk * 8 + b) * KP + k] = c2a[b];
        }
        return;
    }
    // basisD: Z[k2][t], ZT[t][k2], 64k x 64t tiles
    {
        int i0 = bx - 472;                    // 0..1519
        int kb = i0 / 20, tb = i0 % 20;
        int k0 = kb * 64, t0 = tb * 64;
        int kk = tid >> 2, tq = tid & 3;
        int k = k0 + kk;
        float2 r1 = rot1t[k];
        float2 acc = r1;                      // angle w*1
        {   // * rot8^tq
            float2 p = rot8t[k];
            if (tq & 1) acc = cmul(acc, p);
            p = cmul(p, p);
            if (tq & 2) acc = cmul(acc, p);
        }
        {   // * rot64^tb
            int e = tb;
            float2 p = rot64t[k];
            while (e) { if (e & 1) acc = cmul(acc, p); p = cmul(p, p); e >>= 1; }
        }
        bool kv = (k < K);
        float2 r32 = rot32t[k];
#pragma unroll
        for (int j = 0; j < 2; j++) {
            float2 r = acc;
            H8 hc, hs;
#pragma unroll
            for (int d = 0; d < 8; d++) {
                int tl = tq * 8 + j * 32 + d;
                bool ok = kv && (t0 + tl < T_);
                float c = ok ? r.x : 0.f, s = ok ? r.y : 0.f;
                hc.e[d] = (_Float16)c; hs.e[d] = (_Float16)s;
                HP pk; pk.hh[0] = hc.e[d]; pk.hh[1] = hs.e[d];
                *(unsigned*)&sZT[tl * 136 + 2 * kk] = pk.u;
                r = cmul(r, r1);
            }
            int ch = tq + 4 * j;              // chunk 0..7
            int rc = 2 * kk, rs = 2 * kk + 1;
            *(float4*)&sZ[rc * 80 + ((ch ^ (rc & 7)) << 3)] = hc.v;
            *(float4*)&sZ[rs * 80 + ((ch ^ (rs & 7)) << 3)] = hs.v;
            acc = cmul(acc, r32);
        }
        __syncthreads();
        // Z out: 128 rows x 128B
        {
            int c8 = tid & 7, rr = tid >> 3;  // rr 0..31
#pragma unroll
            for (int p = 0; p < 4; p++) {
                int row = p * 32 + rr;
                float4 v = *(const float4*)&sZ[row * 80 + ((c8 ^ (row & 7)) << 3)];
                *(float4*)&Zb[(size_t)(2 * k0 + row) * TP2 + t0 + c8 * 8] = v;
            }
        }
        // ZT out: 64 rows x 256B
        {
            int c16 = tid & 15, rr = tid >> 4; // rr 0..15
#pragma unroll
            for (int p = 0; p < 4; p++) {
                int row = p * 16 + rr;
                float4 v = *(const float4*)&sZT[row * 136 + c16 * 8];
                *(float4*)&ZT[(size_t)(t0 + row) * K2P + 2 * k0 + c16 * 8] = v;
            }
        }
    }
}

// ---------------- GEMM1: 64(m) x 128(k2) tiles, fused phi + LS-combine ----------------
// waves 2x2: wave tile 32(m) x 64(k2); 8 MFMA/step/wave
__global__ __launch_bounds__(256, 3) void gemm1x(
    const _Float16* __restrict__ dm, const _Float16* __restrict__ Zb,
    const float* __restrict__ partS, const float* __restrict__ partC,
    const float* __restrict__ cnt,
    _Float16* __restrict__ Wout) {
    __shared__ _Float16 lds[24576];   // 48KB: 2 bufs x (A 8KB | B 16KB)
    char* ldsb = (char*)lds;
    int bx = blockIdx.x;                    // 608 = 8 XCD * 76
    int g = (bx & 7) * 76 + (bx >> 3);      // bijective, XCD-chunked
    int mt = g & 7, nt = g >> 3;
    int m0 = mt * 64, n0 = nt * 128;
    int tid = threadIdx.x, lane = tid & 63, wv = tid >> 6;
    int ra = lane & 31, kg = lane >> 5, x = ra & 7;
    int wm = (wv & 1) * 32, wn = (wv >> 1) * 64;
    int r0 = wm + ra, q0 = wn + ra;
    f32x16 acc0 = Z16v, acc1 = Z16v;
    int sAo[2], sBo[4];
#pragma unroll
    for (int i = 0; i < 2; i++) {
        int g8 = i * 256 + tid;
        int r = g8 >> 3, c = g8 & 7;
        sAo[i] = r * 2560 + ((c ^ (r & 7)) << 4);
    }
#pragma unroll
    for (int i = 0; i < 4; i++) {
        int g8 = i * 256 + tid;
        int r = g8 >> 3, c = g8 & 7;
        sBo[i] = r * 2560 + ((c ^ (r & 7)) << 4);
    }
    const char* pA = (const char*)dm + (size_t)m0 * 2560;
    const char* pB = (const char*)Zb + (size_t)n0 * 2560;
#define STG1(BUFOFF, RC) do {                                                  \
        char* Ld_ = ldsb + (BUFOFF);                                           \
        _Pragma("unroll")                                                      \
        for (int i_ = 0; i_ < 2; i_++)                                         \
            gload16(pA + (RC) + sAo[i_], Ld_ + ((i_ * 256 + tid) << 4));       \
        _Pragma("unroll")                                                      \
        for (int i_ = 0; i_ < 4; i_++)                                         \
            gload16(pB + (RC) + sBo[i_], Ld_ + 8192 + ((i_ * 256 + tid) << 4));\
    } while (0)
    STG1(0, 0);
    __syncthreads();
    int cur = 0;
    for (int step = 0; step < NST1; step++) {
        if (step + 1 < NST1) STG1((cur ^ 1) * 24576, (step + 1) << 7);
        const char* LA = ldsb + cur * 24576;
        const char* LB = LA + 8192;
#pragma unroll
        for (int kc = 0; kc < 4; kc++) {
            int c = kc * 2 + kg;
            h8 a0 = *(const h8*)(LA + ((r0 * 8 + (c ^ x)) << 4));
            h8 b0 = *(const h8*)(LB + ((q0 * 8 + (c ^ x)) << 4));
            h8 b1 = *(const h8*)(LB + (((q0 + 32) * 8 + (c ^ x)) << 4));
            acc0 = MFMA32(a0, b0, acc0);
            acc1 = MFMA32(a0, b1, acc1);
        }
        __syncthreads();
        cur ^= 1;
    }
#undef STG1
    // epilogue: inline phi + LS-combine; wave owns rows m0+wm..+31, cols n0+wn..+63
    int bb = mt;                            // 64-row tile aligns with batch dim
    int colk = lane & 31, rb4 = (lane >> 5) * 4;
    float cn = cnt[bb];
    float cpJ[2], spJ[2], rcJ[2], rsJ[2];
#pragma unroll
    for (int J = 0; J < 2; J++) {
        int k2 = n0 + wn + 32 * J + colk;
        int k = k2 >> 1;
        float s2 = 0.f, c2 = 0.f;
#pragma unroll
        for (int c = 0; c < 8; c++) {
            s2 += partS[(size_t)(c * 8 + bb) * KP + k];
            c2 += partC[(size_t)(c * 8 + bb) * KP + k];
        }
        float phi = 0.5f * atan2f(s2, c2);
        float cp = cosf(phi), sp = sinf(phi);
        float A = 0.5f * (cn + c2), D = 0.5f * (cn - c2), E = 0.5f * s2;
        cpJ[J] = cp; spJ[J] = sp;
        rcJ[J] = 1.f / (cp * cp * A + 2.f * cp * sp * E + sp * sp * D);
        rsJ[J] = 1.f / (sp * sp * A - 2.f * cp * sp * E + cp * cp * D);
    }
#define EPI1(ACC, J) {                                                         \
        int k2 = n0 + wn + 32 * (J) + colk;                                    \
        float cp = cpJ[J], sp = spJ[J];                                        \
        float rc_ = rcJ[J], rs_ = rsJ[J];                                      \
        int par = k2 & 1;                                                      \
        _Pragma("unroll")                                                      \
        for (int reg = 0; reg < 16; reg++) {                                   \
            float own = (ACC)[reg];                                            \
            float oth = __shfl_xor(own, 1);                                    \
            float p = par ? oth : own, q = par ? own : oth;                    \
            float cc = (cp * p + sp * q) * rc_;                                \
            float sc = (cp * q - sp * p) * rs_;                                \
            float val = par ? (sp * cc + cp * sc) : (cp * cc - sp * sc);       \
            int row = m0 + wm + rb4 + (reg & 3) + 8 * (reg >> 2);              \
            Wout[(size_t)row * K2P + k2] = (_Float16)val;                      \
        } }
    EPI1(acc0, 0); EPI1(acc1, 1);
#undef EPI1
}

// ---------------- GEMM2: 128(m) x 64(t) tiles, split-K=8; rpart f16 ----------------
// waves 2x2: wave tile 64(m) x 32(t); 8 MFMA/step/wave
__global__ __launch_bounds__(256, 3) void gemm2x(
    const _Float16* __restrict__ Wm, const _Float16* __restrict__ ZT,
    _Float16* __restrict__ rpart) {
    __shared__ _Float16 lds[24576];   // 48KB: 2 bufs x (A 16KB | B 8KB)
    char* ldsb = (char*)lds;
    int bx = blockIdx.x;                 // 640 = 8 XCD * 80; one sk per XCD
    int sk = bx & 7;
    int g2 = bx >> 3;                    // 0..79
    int mt = g2 & 3, tt = g2 >> 2;       // mt 0..3, tt 0..19
    int m0 = mt * 128, t0 = tt * 64;
    int tid = threadIdx.x, lane = tid & 63, wv = tid >> 6;
    int ra = lane & 31, kg = lane >> 5, x = ra & 7;
    int wm = (wv & 1) * 64, wn = (wv >> 1) * 32;
    int r0 = wm + ra, q0 = wn + ra;
    f32x16 acc0 = Z16v, acc1 = Z16v;
    int sAo[4], sBo[2];
#pragma unroll
    for (int i = 0; i < 4; i++) {
        int g8 = i * 256 + tid;
        int r = g8 >> 3, c = g8 & 7;
        sAo[i] = r * 19456 + ((c ^ (r & 7)) << 4);
    }
#pragma unroll
    for (int i = 0; i < 2; i++) {
        int g8 = i * 256 + tid;
        int r = g8 >> 3, c = g8 & 7;
        sBo[i] = r * 19456 + ((c ^ (r & 7)) << 4);
    }
    const char* pA = (const char*)Wm + (size_t)m0 * 19456 + sk * 2432;
    const char* pB = (const char*)ZT + (size_t)t0 * 19456 + sk * 2432;
#define STG2(BUFOFF, RC) do {                                                  \
        char* Ld_ = ldsb + (BUFOFF);                                           \
        _Pragma("unroll")                                                      \
        for (int i_ = 0; i_ < 4; i_++)                                         \
            gload16(pA + (RC) + sAo[i_], Ld_ + ((i_ * 256 + tid) << 4));       \
        _Pragma("unroll")                                                      \
        for (int i_ = 0; i_ < 2; i_++)                                         \
            gload16(pB + (RC) + sBo[i_], Ld_ + 16384 + ((i_ * 256 + tid) << 4));\
    } while (0)
    STG2(0, 0);
    __syncthreads();
    int cur = 0;
    for (int step = 0; step < NST2; step++) {
        if (step + 1 < NST2) STG2((cur ^ 1) * 24576, (step + 1) << 7);
        const char* LA = ldsb + cur * 24576;
        const char* LB = LA + 16384;
#pragma unroll
        for (int kc = 0; kc < 4; kc++) {
            int c = kc * 2 + kg;
            h8 a0 = *(const h8*)(LA + ((r0 * 8 + (c ^ x)) << 4));
            h8 a1 = *(const h8*)(LA + (((r0 + 32) * 8 + (c ^ x)) << 4));
            h8 b0 = *(const h8*)(LB + ((q0 * 8 + (c ^ x)) << 4));
            acc0 = MFMA32(a0, b0, acc0);
            acc1 = MFMA32(a1, b0, acc1);
        }
        __syncthreads();
        cur ^= 1;
    }
#undef STG2
    int colk = lane & 31, rb4 = (lane >> 5) * 4;
    int t = t0 + wn + colk;
#define EPI2(ACC, I) {                                                         \
        _Pragma("unroll")                                                      \
        for (int reg = 0; reg < 16; reg++) {                                   \
            int row = m0 + wm + 32 * (I) + rb4 + (reg & 3) + 8 * (reg >> 2);   \
            rpart[(size_t)(sk * M_ + row) * TP2 + t] = (_Float16)(ACC)[reg];   \
        } }
    EPI2(acc0, 0); EPI2(acc1, 1);
#undef EPI2
}

// ---------------- normalize + select (f16 rpart) ----------------
__global__ __launch_bounds__(256) void norm3_kernel(
    const _Float16* __restrict__ rpart, const float* __restrict__ data,
    const float* __restrict__ mf, const float* __restrict__ cnt,
    float* __restrict__ out) {
    __shared__ float rsum[T_];
    __shared__ float4 red4[256];
    __shared__ float s_scale;
    int bc = blockIdx.x, b = bc >> 6;
    const size_t rbase = (size_t)bc * TP2;
    const size_t dbase = (size_t)bc * T_;
    const size_t rstr = (size_t)M_ * TP2;
    float sr = 0.f, srr = 0.f, sd = 0.f, sdd = 0.f;
    for (int t = threadIdx.x; t < T_; t += 256) {
        float r = 0.f;
#pragma unroll
        for (int s = 0; s < SPLITK; s++) r += (float)rpart[s * rstr + rbase + t];
        rsum[t] = r;
        float m = mf[b * T_ + t];
        float xv = data[dbase + t];
        sr += r; srr += r * r; sd += xv * m; sdd += xv * xv * m;
    }
    red4[threadIdx.x] = make_float4(sr, srr, sd, sdd);
    __syncthreads();
    for (int w = 128; w > 0; w >>= 1) {
        if (threadIdx.x < w) {
            float4 a = red4[threadIdx.x], c = red4[threadIdx.x + w];
            red4[threadIdx.x] = make_float4(a.x + c.x, a.y + c.y, a.z + c.z, a.w + c.w);
        }
        __syncthreads();
    }
    if (threadIdx.x == 0) {
        float4 v = red4[0];
        float cn = cnt[b];
        float varr = (v.y - v.x * v.x / (float)T_) / (float)(T_ - 1);
        float vard = (v.w - v.z * v.z / cn) / (cn - 1.f);
        s_scale = sqrtf(vard / varr);
    }
    __syncthreads();
    float scale = s_scale;
    for (int t = threadIdx.x; t < T_; t += 256) {
        float m = mf[b * T_ + t];
        out[dbase + t] = (m > 0.5f) ? data[dbase + t] : rsum[t] * scale;
    }
}

extern "C" void kernel_launch(void* const* d_in, const int* in_sizes, int n_in,
                              void* d_out, int out_size, void* d_ws, size_t ws_size,
                              hipStream_t stream) {
    const float* data = (const float*)d_in[0];
    const void* mask = d_in[1];
    float* out = (float*)d_out;

    // Replicate numpy arange length computation exactly (double precision).
    const double timespan = 1.0 * (T_ + 1) - 1.0;               // 1200
    const double fstep = 1.0 / (timespan * 8.0);                // OSFREQ = 8
    const double stop = (1.0 * (double)T_) / (2.0 * timespan) + fstep;
    const int K = (int)ceil((stop - fstep) / fstep);            // 4800 (or 4801)

    char* w = (char*)d_ws;
    auto alloc = [&](size_t nbytes) {
        char* p = w;
        w += ((nbytes + 255) / 256) * 256;
        return p;
    };
    float*     mf    = (float*)    alloc((size_t)B_ * T_ * 4);
    float*     cnt   = (float*)    alloc(B_ * 4);
    float2*    rot1  = (float2*)   alloc((size_t)KP * 8);
    float2*    rot8  = (float2*)   alloc((size_t)KP * 8);
    float2*    rot32 = (float2*)   alloc((size_t)KP * 8);
    float2*    rot64 = (float2*)   alloc((size_t)KP * 8);
    float2*    rot2  = (float2*)   alloc((size_t)KP * 8);
    float2*    rot304= (float2*)   alloc((size_t)KP * 8);
    float*     partS = (float*)    alloc((size_t)64 * KP * 4);
    float*     partC = (float*)    alloc((size_t)64 * KP * 4);
    _Float16*  dm_h  = (_Float16*) alloc((size_t)M_ * TP2 * 2);
    _Float16*  Z     = (_Float16*) alloc((size_t)K2P * TP2 * 2);
    _Float16*  ZT    = (_Float16*) alloc((size_t)TP2 * K2P * 2);
    _Float16*  W     = (_Float16*) alloc((size_t)M_ * K2P * 2);
    _Float16*  rpart = (_Float16*) alloc((size_t)SPLITK * M_ * TP2 * 2);
    (void)ws_size; (void)in_sizes; (void)n_in; (void)out_size;

    seed_kernel<<<125, 256, 0, stream>>>(mask, mf, cnt, rot1, rot8, rot32,
                                         rot64, rot2, rot304, fstep);
    prep2_kernel<<<1992, 256, 0, stream>>>(data, mf, rot1, rot8, rot32, rot64,
                                           rot2, rot304, dm_h, partS, partC, Z, ZT, K);
    gemm1x<<<608, 256, 0, stream>>>(dm_h, Z, partS, partC, cnt, W);
    gemm2x<<<640, 256, 0, stream>>>(W, ZT, rpart);
    norm3_kernel<<<M_, 256, 0, stream>>>(rpart, data, mf, cnt, out);
}